// Round 3
// baseline (19959.912 us; speedup 1.0000x reference)
//
#include <hip/hip_runtime.h>
#include <hip/hip_bf16.h>

// Fused block-sparse FFN:  out = gelu(x @ (W1*M1)^T + b1) @ (W2*M2)^T + b2
// x:[36928,768] f32, W1:[3072,768], W2:[768,3072], masks int32 0/1, 8x8 blocks, ~10% dense.
// One block = 8 rows. x tile f32 + h chunk bf16 in static LDS (49.4 KB -> 3 blocks/CU).
// h computed in 2 chunks of 1536; out held in 24 reg accumulators/lane across chunks.
// Wave-uniform sparsity: wave iterates whole 8-wide blocks; lane = (row<<3)|col_in_block.

#define MROW 8
#define XPITCH 772            // f32 elems: row byte stride 3088
#define FCHUNK 1536
#define FBLK 192              // 8-wide f-blocks per chunk
#define HPITCH 1544           // bf16 elems: row byte stride 3088

__device__ __forceinline__ float bflo(unsigned u) { return __uint_as_float(u << 16); }
__device__ __forceinline__ float bfhi(unsigned u) { return __uint_as_float(u & 0xffff0000u); }
__device__ __forceinline__ float gelu_exact(float v) {
    return 0.5f * v * (1.0f + erff(v * 0.70710678118654752f));
}

__global__ __launch_bounds__(256, 3)
void bsffn_fused(const float* __restrict__ x,
                 const float* __restrict__ W1, const float* __restrict__ b1,
                 const float* __restrict__ W2, const float* __restrict__ b2,
                 const int* __restrict__ mask1, const int* __restrict__ mask2,
                 float* __restrict__ out)
{
    __shared__ __align__(16) float xs[MROW * XPITCH];            // 24704 B
    __shared__ __align__(16) __hip_bfloat16 hs[MROW * HPITCH];   // 24704 B

    const int tid  = threadIdx.x;
    const int wave = tid >> 6;
    const int lane = tid & 63;
    const int fin  = lane & 7;   // column within 8-wide block
    const int rh   = lane >> 3;  // row 0..7
    const long rowBase = (long)blockIdx.x * MROW;

    // ---- Phase 1: stage x tile (coalesced float4 -> padded LDS) ----
    const float4* x4 = (const float4*)(x + rowBase * 768);
    #pragma unroll
    for (int i = 0; i < 6; ++i) {
        int idx = tid + i * 256;               // 1536 float4s
        int r = idx / 192, c4 = idx % 192;
        float4 v = x4[idx];
        *(float4*)&xs[r * XPITCH + c4 * 4] = v;
    }

    float acc[24];
    #pragma unroll
    for (int j = 0; j < 24; ++j) acc[j] = 0.f;

    __syncthreads();

    for (int chunk = 0; chunk < 2; ++chunk) {
        // ---- Phase 2: h chunk = gelu(x @ (W1*M1)^T + b1) -> bf16 LDS ----
        for (int t = 0; t < FBLK / 4; ++t) {          // 48 f-blocks per wave
            const int fbl = wave * 48 + t;            // wave-uniform
            const int fg  = chunk * FCHUNK + fbl * 8 + fin;
            const float* wrow = W1 + (long)fg * 768;
            const int* m = mask1 + (long)(chunk * FBLK + fbl) * 96;
            float ae = 0.f, ao = 0.f;
            for (int db = 0; db < 96; ++db) {
                if (m[db]) {                          // wave-uniform skip
                    const int c = db * 8;
                    float4 w0 = *(const float4*)(wrow + c);
                    float4 w1 = *(const float4*)(wrow + c + 4);
                    float4 x0 = *(const float4*)&xs[rh * XPITCH + c];
                    float4 x1 = *(const float4*)&xs[rh * XPITCH + c + 4];
                    ae = fmaf(x0.x, w0.x, ae); ae = fmaf(x0.y, w0.y, ae);
                    ae = fmaf(x0.z, w0.z, ae); ae = fmaf(x0.w, w0.w, ae);
                    ao = fmaf(x1.x, w1.x, ao); ao = fmaf(x1.y, w1.y, ao);
                    ao = fmaf(x1.z, w1.z, ao); ao = fmaf(x1.w, w1.w, ao);
                }
            }
            float v = gelu_exact(ae + ao + b1[fg]);
            hs[rh * HPITCH + fbl * 8 + fin] = __float2bfloat16(v);
        }
        __syncthreads();

        // ---- Phase 3: accumulate out partials from this h chunk ----
        #pragma unroll
        for (int j = 0; j < 24; ++j) {                // static acc indexing
            const int dbr = wave * 24 + j;            // wave-uniform
            const int d   = dbr * 8 + fin;
            const float* wrow = W2 + (long)d * 3072 + chunk * FCHUNK;
            const int* m = mask2 + (long)dbr * 384 + chunk * FBLK;
            float a = acc[j];
            for (int fbl = 0; fbl < FBLK; ++fbl) {
                if (m[fbl]) {                         // wave-uniform skip
                    const int c = fbl * 8;
                    float4 w0 = *(const float4*)(wrow + c);
                    float4 w1 = *(const float4*)(wrow + c + 4);
                    uint4 h4 = *(const uint4*)&hs[rh * HPITCH + c];  // 8 bf16
                    a = fmaf(bflo(h4.x), w0.x, a); a = fmaf(bfhi(h4.x), w0.y, a);
                    a = fmaf(bflo(h4.y), w0.z, a); a = fmaf(bfhi(h4.y), w0.w, a);
                    a = fmaf(bflo(h4.z), w1.x, a); a = fmaf(bfhi(h4.z), w1.y, a);
                    a = fmaf(bflo(h4.w), w1.z, a); a = fmaf(bfhi(h4.w), w1.w, a);
                }
            }
            acc[j] = a;
        }
        if (chunk == 0) __syncthreads();              // before h overwrite
    }

    // ---- Epilogue: bias + store ----
    #pragma unroll
    for (int j = 0; j < 24; ++j) {
        const int d = (wave * 24 + j) * 8 + fin;
        out[(rowBase + rh) * 768 + d] = acc[j] + b2[d];
    }
}

extern "C" void kernel_launch(void* const* d_in, const int* in_sizes, int n_in,
                              void* d_out, int out_size, void* d_ws, size_t ws_size,
                              hipStream_t stream) {
    const float* x     = (const float*)d_in[0];
    const float* W1    = (const float*)d_in[1];
    const float* b1    = (const float*)d_in[2];
    const float* W2    = (const float*)d_in[3];
    const float* b2    = (const float*)d_in[4];
    const int*   mask1 = (const int*)d_in[5];   // [384,96] int32 0/1
    const int*   mask2 = (const int*)d_in[6];   // [96,384]
    float* out = (float*)d_out;

    const int rows = in_sizes[0] / 768;         // 36928
    const int nblk = rows / MROW;               // 4616 (exact)

    bsffn_fused<<<nblk, 256, 0, stream>>>(x, W1, b1, W2, b2, mask1, mask2, out);
}

// Round 4
// 7994.311 us; speedup vs baseline: 2.4968x; 2.4968x over previous
//
#include <hip/hip_runtime.h>
#include <hip/hip_bf16.h>

// Fused block-sparse FFN:  out = gelu(x @ (W1*M1)^T + b1) @ (W2*M2)^T + b2
// x:[36928,768] f32, W1:[3072,768], W2:[768,3072], masks int32 0/1, 8x8 blocks, ~10% dense.
// One block = 8 rows. x tile f32 + h chunk bf16 in static LDS (49.4 KB -> 3 blocks/CU).
// v3: ballot-packed wave-uniform bitmasks + ctz iteration over set bits only (no
// per-iteration load->branch chain), 2-deep software pipeline in the hit loop.

#define MROW 8
#define XPITCH 772            // f32 elems: row byte stride 3088
#define FCHUNK 1536
#define FBLK 192              // 8-wide f-blocks per chunk
#define HPITCH 1544           // bf16 elems: row byte stride 3088

__device__ __forceinline__ float bflo(unsigned u) { return __uint_as_float(u << 16); }
__device__ __forceinline__ float bfhi(unsigned u) { return __uint_as_float(u & 0xffff0000u); }
__device__ __forceinline__ float gelu_exact(float v) {
    return 0.5f * v * (1.0f + erff(v * 0.70710678118654752f));
}

// 8 fp32 FMAs: acc pair += x(8 floats as 2 float4) * w(2 float4)
#define FMA8_F32(ae, ao, x0, x1, w0, w1)                           \
    ae = fmaf(x0.x, w0.x, ae); ae = fmaf(x0.y, w0.y, ae);          \
    ae = fmaf(x0.z, w0.z, ae); ae = fmaf(x0.w, w0.w, ae);          \
    ao = fmaf(x1.x, w1.x, ao); ao = fmaf(x1.y, w1.y, ao);          \
    ao = fmaf(x1.z, w1.z, ao); ao = fmaf(x1.w, w1.w, ao);

// 8 FMAs from 8 bf16 (uint4) * w(2 float4)
#define FMA8_BF16(a, h4, w0, w1)                                   \
    a = fmaf(bflo(h4.x), w0.x, a); a = fmaf(bfhi(h4.x), w0.y, a);  \
    a = fmaf(bflo(h4.y), w0.z, a); a = fmaf(bfhi(h4.y), w0.w, a);  \
    a = fmaf(bflo(h4.z), w1.x, a); a = fmaf(bfhi(h4.z), w1.y, a);  \
    a = fmaf(bflo(h4.w), w1.z, a); a = fmaf(bfhi(h4.w), w1.w, a);

__global__ __launch_bounds__(256, 3)
void bsffn_fused(const float* __restrict__ x,
                 const float* __restrict__ W1, const float* __restrict__ b1,
                 const float* __restrict__ W2, const float* __restrict__ b2,
                 const int* __restrict__ mask1, const int* __restrict__ mask2,
                 float* __restrict__ out)
{
    __shared__ __align__(16) float xs[MROW * XPITCH];            // 24704 B
    __shared__ __align__(16) __hip_bfloat16 hs[MROW * HPITCH];   // 24704 B

    const int tid  = threadIdx.x;
    const int wave = tid >> 6;
    const int lane = tid & 63;
    const int fin  = lane & 7;   // column within 8-wide block
    const int rh   = lane >> 3;  // row 0..7
    const long rowBase = (long)blockIdx.x * MROW;

    // ---- Phase 1: stage x tile (coalesced float4 -> padded LDS) ----
    const float4* x4 = (const float4*)(x + rowBase * 768);
    #pragma unroll
    for (int i = 0; i < 6; ++i) {
        int idx = tid + i * 256;               // 1536 float4s
        int r = idx / 192, c4 = idx % 192;
        float4 v = x4[idx];
        *(float4*)&xs[r * XPITCH + c4 * 4] = v;
    }

    float acc[24];
    #pragma unroll
    for (int j = 0; j < 24; ++j) acc[j] = 0.f;

    __syncthreads();

    for (int chunk = 0; chunk < 2; ++chunk) {
        // ---- Phase 2: h chunk = gelu(x @ (W1*M1)^T + b1) -> bf16 LDS ----
        for (int t = 0; t < 48; ++t) {
            const int fbl = wave * 48 + t;            // 0..191 within chunk
            const int mrow = chunk * FBLK + fbl;      // global f-block row
            const int fg = mrow * 8 + fin;
            const float* wrow = W1 + (long)fg * 768;
            const int* m = mask1 + (long)mrow * 96;
            // pack 96 mask words -> wave-uniform bitmasks (SGPR)
            unsigned long long mb0 = __ballot(m[lane] != 0);                        // db 0..63
            unsigned long long mb1 = __ballot(m[64 + (lane & 31)] != 0) & 0xffffffffull; // db 64..95
            float ae = 0.f, ao = 0.f;
            #pragma unroll
            for (int half = 0; half < 2; ++half) {
                unsigned long long bits = half ? mb1 : mb0;
                const int base = half * 64;
                if (bits) {
                    int k = __builtin_ctzll(bits); bits &= bits - 1;
                    const float* wp = wrow + (base + k) * 8;
                    const float* xp = &xs[rh * XPITCH + (base + k) * 8];
                    float4 w0 = *(const float4*)wp,       w1 = *(const float4*)(wp + 4);
                    float4 x0 = *(const float4*)xp,       x1 = *(const float4*)(xp + 4);
                    while (bits) {
                        int kn = __builtin_ctzll(bits); bits &= bits - 1;
                        const float* wpn = wrow + (base + kn) * 8;
                        const float* xpn = &xs[rh * XPITCH + (base + kn) * 8];
                        float4 nw0 = *(const float4*)wpn, nw1 = *(const float4*)(wpn + 4);
                        float4 nx0 = *(const float4*)xpn, nx1 = *(const float4*)(xpn + 4);
                        FMA8_F32(ae, ao, x0, x1, w0, w1)
                        w0 = nw0; w1 = nw1; x0 = nx0; x1 = nx1;
                    }
                    FMA8_F32(ae, ao, x0, x1, w0, w1)
                }
            }
            float v = gelu_exact(ae + ao + b1[fg]);
            hs[rh * HPITCH + fbl * 8 + fin] = __float2bfloat16(v);
        }
        __syncthreads();

        // ---- Phase 3: accumulate out partials from this h chunk ----
        #pragma unroll
        for (int j = 0; j < 24; ++j) {                // static acc indexing
            const int dbr = wave * 24 + j;            // wave-uniform
            const int d   = dbr * 8 + fin;
            const float* wrow = W2 + (long)d * 3072 + chunk * FCHUNK;
            const int* m = mask2 + (long)dbr * 384 + chunk * FBLK;
            float a = acc[j];
            #pragma unroll
            for (int part = 0; part < 3; ++part) {    // 192 bits = 3 x 64
                unsigned long long bits = __ballot(m[part * 64 + lane] != 0);
                const int base = part * 64;
                if (bits) {
                    int k = __builtin_ctzll(bits); bits &= bits - 1;
                    const float* wp = wrow + (base + k) * 8;
                    const __hip_bfloat16* hp = &hs[rh * HPITCH + (base + k) * 8];
                    float4 w0 = *(const float4*)wp, w1 = *(const float4*)(wp + 4);
                    uint4 h4 = *(const uint4*)hp;
                    while (bits) {
                        int kn = __builtin_ctzll(bits); bits &= bits - 1;
                        const float* wpn = wrow + (base + kn) * 8;
                        const __hip_bfloat16* hpn = &hs[rh * HPITCH + (base + kn) * 8];
                        float4 nw0 = *(const float4*)wpn, nw1 = *(const float4*)(wpn + 4);
                        uint4 nh4 = *(const uint4*)hpn;
                        FMA8_BF16(a, h4, w0, w1)
                        w0 = nw0; w1 = nw1; h4 = nh4;
                    }
                    FMA8_BF16(a, h4, w0, w1)
                }
            }
            acc[j] = a;
        }
        if (chunk == 0) __syncthreads();              // before h overwrite
    }

    // ---- Epilogue: bias + store ----
    #pragma unroll
    for (int j = 0; j < 24; ++j) {
        const int d = (wave * 24 + j) * 8 + fin;
        out[(rowBase + rh) * 768 + d] = acc[j] + b2[d];
    }
}

extern "C" void kernel_launch(void* const* d_in, const int* in_sizes, int n_in,
                              void* d_out, int out_size, void* d_ws, size_t ws_size,
                              hipStream_t stream) {
    const float* x     = (const float*)d_in[0];
    const float* W1    = (const float*)d_in[1];
    const float* b1    = (const float*)d_in[2];
    const float* W2    = (const float*)d_in[3];
    const float* b2    = (const float*)d_in[4];
    const int*   mask1 = (const int*)d_in[5];   // [384,96] int32 0/1
    const int*   mask2 = (const int*)d_in[6];   // [96,384]
    float* out = (float*)d_out;

    const int rows = in_sizes[0] / 768;         // 36928
    const int nblk = rows / MROW;               // 4616 (exact)

    bsffn_fused<<<nblk, 256, 0, stream>>>(x, W1, b1, W2, b2, mask1, mask2, out);
}

// Round 5
// 652.111 us; speedup vs baseline: 30.6081x; 12.2591x over previous
//
#include <hip/hip_runtime.h>
#include <hip/hip_bf16.h>

// Block-sparse FFN via compacted-weight MFMA.
//   out = gelu(x @ (W1*M1)^T + b1) @ (W2*M2)^T + b2
// Prep kernel: per 16-row weight group, union-compact nonzero 8-blocks (ballot/rank),
// gather masked weights to bf16 MFMA B-tiles in d_ws. Main kernel: 32 x-rows/block,
// mfma_f32_16x16x32_bf16 over compacted K; x,h bf16 in LDS; fc2 lists pre-split at
// the h-chunk boundary (zero-padded to K=32 groups).

typedef __attribute__((ext_vector_type(8))) short short8;
typedef __attribute__((ext_vector_type(4))) float f32x4;
typedef unsigned long long u64;

#define DIM 768
#define FF 3072
#define NF16 192            // FF/16  (fc1 groups)
#define ND16 48             // DIM/16 (fc2 groups)
#define NDB 96              // DIM/8
#define NFB 384             // FF/8
#define MR 32               // x rows per block
#define XP 776              // xs pitch (bf16): 768+8  (row stride 1552 B)
#define HCH 1536            // h chunk width
#define HP 1544             // hs pitch (bf16): 1536+8 (row stride 3088 B)
#define W1C_STRIDE 12288    // elems per F group: 96 slots * 128
#define W2C_STRIDE 50176    // elems per G group: 392 slots * 128
#define IDX2_STRIDE 392

#define W1C_TOT (NF16 * W1C_STRIDE)   // 2359296 elems
#define W2C_TOT (ND16 * W2C_STRIDE)   // 2408448 elems
#define IDX1_TOT (NF16 * 96)          // 18432
#define IDX2_TOT (ND16 * IDX2_STRIDE) // 18816

__device__ __forceinline__ float gelu_exact(float v) {
    return 0.5f * v * (1.0f + erff(v * 0.70710678118654752f));
}
__device__ __forceinline__ unsigned short f2bs(float f) {
    union { __hip_bfloat16 h; unsigned short u; } cv;
    cv.h = __float2bfloat16(f);
    return cv.u;
}

// ---------------- preprocessing: compact masked weights to bf16 tiles ----------------
__global__ __launch_bounds__(256)
void bsffn_prep(const float* __restrict__ W1, const float* __restrict__ W2,
                const int* __restrict__ mask1, const int* __restrict__ mask2,
                __hip_bfloat16* __restrict__ W1c, __hip_bfloat16* __restrict__ W2c,
                unsigned short* __restrict__ idx1, unsigned short* __restrict__ idx2,
                int* __restrict__ cnt1p, int* __restrict__ off2)
{
    __shared__ unsigned short sidx[400];
    __shared__ int sc[4];
    const int tid = threadIdx.x;
    const int l = tid & 63;
    const int g = blockIdx.x;

    if (g < NF16) {                       // ---- fc1 group F ----
        const int F = g;
        const int* r0 = mask1 + (2 * F) * NDB;
        const int* r1 = r0 + NDB;
        if (tid < 64) {
            bool ua = (r0[l] | r1[l]) != 0;
            u64 ba = __ballot(ua);
            bool ub = (l < 32) && ((r0[64 + l] | r1[64 + l]) != 0);
            u64 bb = __ballot(ub);
            int ca = __popcll(ba);
            if (ua) sidx[__popcll(ba & ((1ull << l) - 1ull))] = (unsigned short)l;
            if (ub) sidx[ca + __popcll(bb & ((1ull << l) - 1ull))] = (unsigned short)(64 + l);
            int cnt = ca + __popcll(bb);
            int cntp = (cnt + 3) & ~3;
            if (l == 0) {
                for (int i = cnt; i < cntp; ++i) sidx[i] = 0;
                sc[0] = cnt; sc[1] = cntp;
                cnt1p[F] = cntp;
            }
        }
        __syncthreads();
        const int cnt = sc[0], cntp = sc[1];
        if (tid < cntp) idx1[F * 96 + tid] = sidx[tid];
        for (int e = tid; e < cntp * 128; e += 256) {
            int slot = e >> 7, r = (e >> 3) & 15, j = e & 7;
            int db = sidx[slot];
            float w = 0.f;
            if (slot < cnt && mask1[(2 * F + (r >> 3)) * NDB + db])
                w = W1[(long)(F * 16 + r) * DIM + db * 8 + j];
            W1c[(long)F * W1C_STRIDE + e] = __float2bfloat16(w);
        }
    } else {                              // ---- fc2 group G ----
        const int G = g - NF16;
        const int* r0 = mask2 + (2 * G) * NFB;
        const int* r1 = r0 + NFB;
        if (tid < 64) {
            u64 bs[6]; int cc[6];
            #pragma unroll
            for (int p = 0; p < 6; ++p) {
                int c = p * 64 + l;
                bs[p] = __ballot((r0[c] | r1[c]) != 0);
                cc[p] = __popcll(bs[p]);
            }
            int cnt0 = cc[0] + cc[1] + cc[2];
            int cnt1 = cc[3] + cc[4] + cc[5];
            int cnt0p = (cnt0 + 3) & ~3;
            int cnt1pp = (cnt1 + 3) & ~3;
            int pre = 0;
            #pragma unroll
            for (int p = 0; p < 3; ++p) {
                if ((bs[p] >> l) & 1ull)
                    sidx[pre + __popcll(bs[p] & ((1ull << l) - 1ull))] = (unsigned short)(p * 64 + l);
                pre += cc[p];
            }
            pre = cnt0p;
            #pragma unroll
            for (int p = 3; p < 6; ++p) {
                if ((bs[p] >> l) & 1ull)
                    sidx[pre + __popcll(bs[p] & ((1ull << l) - 1ull))] = (unsigned short)(p * 64 + l);
                pre += cc[p];
            }
            if (l == 0) {
                for (int i = cnt0; i < cnt0p; ++i) sidx[i] = 0;          // pad -> fb 0 (chunk0)
                for (int i = cnt0p + cnt1; i < cnt0p + cnt1pp; ++i) sidx[i] = 192; // pad -> fb 192 (chunk1)
                sc[0] = cnt0; sc[1] = cnt0p; sc[2] = cnt1; sc[3] = cnt0p + cnt1pp;
                off2[G * 3 + 0] = 0;
                off2[G * 3 + 1] = cnt0p;
                off2[G * 3 + 2] = cnt0p + cnt1pp;
            }
        }
        __syncthreads();
        const int cnt0 = sc[0], cnt0p = sc[1], cnt1 = sc[2], total = sc[3];
        if (tid < total) idx2[G * IDX2_STRIDE + tid] = sidx[tid];
        for (int e = tid; e < total * 128; e += 256) {
            int slot = e >> 7, r = (e >> 3) & 15, j = e & 7;
            int fb = sidx[slot];
            bool live = (slot < cnt0) || (slot >= cnt0p && slot < cnt0p + cnt1);
            float w = 0.f;
            if (live && mask2[(2 * G + (r >> 3)) * NFB + fb])
                w = W2[(long)(G * 16 + r) * FF + fb * 8 + j];
            W2c[(long)G * W2C_STRIDE + e] = __float2bfloat16(w);
        }
    }
}

// ---------------- main fused kernel ----------------
__global__ __launch_bounds__(512, 2)
void bsffn_main(const float* __restrict__ x,
                const float* __restrict__ b1, const float* __restrict__ b2,
                const unsigned short* __restrict__ W1c, const unsigned short* __restrict__ W2c,
                const unsigned short* __restrict__ idx1, const unsigned short* __restrict__ idx2,
                const int* __restrict__ cnt1p, const int* __restrict__ off2,
                float* __restrict__ out)
{
    __shared__ __align__(16) unsigned short xs[MR * XP];   // 49,664 B
    __shared__ __align__(16) unsigned short hs[MR * HP];   // 98,816 B

    const int tid = threadIdx.x;
    const int wave = tid >> 6;
    const int l = tid & 63;
    const int l15 = l & 15;
    const int lg = l >> 4;                 // k-slot subgroup 0..3
    const long rowBase = (long)blockIdx.x * MR;

    // ---- stage x tile -> bf16 LDS ----
    {
        const float* xr = x + rowBase * DIM;
        #pragma unroll
        for (int i = 0; i < 6; ++i) {
            int e = tid + i * 512;         // 0..3071 : 32 rows x 96 col-groups(8)
            int row = e / 96, c8 = e % 96;
            const float4 v0 = *(const float4*)(xr + row * DIM + c8 * 8);
            const float4 v1 = *(const float4*)(xr + row * DIM + c8 * 8 + 4);
            uint4 wv;
            wv.x = (unsigned)f2bs(v0.x) | ((unsigned)f2bs(v0.y) << 16);
            wv.y = (unsigned)f2bs(v0.z) | ((unsigned)f2bs(v0.w) << 16);
            wv.z = (unsigned)f2bs(v1.x) | ((unsigned)f2bs(v1.y) << 16);
            wv.w = (unsigned)f2bs(v1.z) | ((unsigned)f2bs(v1.w) << 16);
            *(uint4*)&xs[row * XP + c8 * 8] = wv;
        }
    }

    f32x4 acc[6][2];
    #pragma unroll
    for (int t = 0; t < 6; ++t) {
        acc[t][0] = (f32x4){0.f, 0.f, 0.f, 0.f};
        acc[t][1] = (f32x4){0.f, 0.f, 0.f, 0.f};
    }

    __syncthreads();

    for (int chunk = 0; chunk < 2; ++chunk) {
        // ---- fc1: h[:, chunk*1536 .. +1536) = gelu(x W1^T + b1) ----
        for (int t = 0; t < 12; ++t) {
            const int Fl = wave + t * 8;           // 0..95 local f16-row
            const int F = chunk * 96 + Fl;
            const int cnt = cnt1p[F];
            const unsigned short* idxF = idx1 + F * 96;
            const unsigned short* wb = W1c + (long)F * W1C_STRIDE + lg * 128 + l15 * 8;
            f32x4 c0 = {0.f, 0.f, 0.f, 0.f}, c1 = {0.f, 0.f, 0.f, 0.f};
            if (cnt > 0) {
                ushort4 iv = *(const ushort4*)(idxF);
                int my = lg == 0 ? iv.x : lg == 1 ? iv.y : lg == 2 ? iv.z : iv.w;
                short8 a0 = *(const short8*)&xs[l15 * XP + my * 8];
                short8 a1 = *(const short8*)&xs[(16 + l15) * XP + my * 8];
                short8 b = *(const short8*)(wb);
                for (int s0 = 4; s0 < cnt; s0 += 4) {
                    ushort4 niv = *(const ushort4*)(idxF + s0);
                    int nmy = lg == 0 ? niv.x : lg == 1 ? niv.y : lg == 2 ? niv.z : niv.w;
                    short8 na0 = *(const short8*)&xs[l15 * XP + nmy * 8];
                    short8 na1 = *(const short8*)&xs[(16 + l15) * XP + nmy * 8];
                    short8 nb = *(const short8*)(wb + s0 * 128);
                    c0 = __builtin_amdgcn_mfma_f32_16x16x32_bf16(a0, b, c0, 0, 0, 0);
                    c1 = __builtin_amdgcn_mfma_f32_16x16x32_bf16(a1, b, c1, 0, 0, 0);
                    a0 = na0; a1 = na1; b = nb;
                }
                c0 = __builtin_amdgcn_mfma_f32_16x16x32_bf16(a0, b, c0, 0, 0, 0);
                c1 = __builtin_amdgcn_mfma_f32_16x16x32_bf16(a1, b, c1, 0, 0, 0);
            }
            const float bias = b1[F * 16 + l15];
            #pragma unroll
            for (int r = 0; r < 4; ++r) {
                int row0 = lg * 4 + r;             // D: col=lane&15, row=(lane>>4)*4+reg
                hs[row0 * HP + Fl * 16 + l15] = f2bs(gelu_exact(c0[r] + bias));
                hs[(16 + row0) * HP + Fl * 16 + l15] = f2bs(gelu_exact(c1[r] + bias));
            }
        }
        __syncthreads();

        // ---- fc2: accumulate out partials from this h chunk ----
        const int cb = chunk * 192;
        #pragma unroll
        for (int t = 0; t < 6; ++t) {
            const int G = wave + t * 8;
            const int sbeg = off2[G * 3 + chunk];
            const int send = off2[G * 3 + chunk + 1];
            const unsigned short* idxG = idx2 + G * IDX2_STRIDE;
            const unsigned short* wb = W2c + (long)G * W2C_STRIDE + lg * 128 + l15 * 8;
            f32x4 c0 = acc[t][0], c1 = acc[t][1];
            if (send > sbeg) {
                ushort4 iv = *(const ushort4*)(idxG + sbeg);
                int my = (lg == 0 ? iv.x : lg == 1 ? iv.y : lg == 2 ? iv.z : iv.w) - cb;
                short8 a0 = *(const short8*)&hs[l15 * HP + my * 8];
                short8 a1 = *(const short8*)&hs[(16 + l15) * HP + my * 8];
                short8 b = *(const short8*)(wb + sbeg * 128);
                for (int s = sbeg + 4; s < send; s += 4) {
                    ushort4 niv = *(const ushort4*)(idxG + s);
                    int nmy = (lg == 0 ? niv.x : lg == 1 ? niv.y : lg == 2 ? niv.z : niv.w) - cb;
                    short8 na0 = *(const short8*)&hs[l15 * HP + nmy * 8];
                    short8 na1 = *(const short8*)&hs[(16 + l15) * HP + nmy * 8];
                    short8 nb = *(const short8*)(wb + s * 128);
                    c0 = __builtin_amdgcn_mfma_f32_16x16x32_bf16(a0, b, c0, 0, 0, 0);
                    c1 = __builtin_amdgcn_mfma_f32_16x16x32_bf16(a1, b, c1, 0, 0, 0);
                    a0 = na0; a1 = na1; b = nb;
                }
                c0 = __builtin_amdgcn_mfma_f32_16x16x32_bf16(a0, b, c0, 0, 0, 0);
                c1 = __builtin_amdgcn_mfma_f32_16x16x32_bf16(a1, b, c1, 0, 0, 0);
            }
            acc[t][0] = c0; acc[t][1] = c1;
        }
        __syncthreads();
    }

    // ---- epilogue: bias + store ----
    #pragma unroll
    for (int t = 0; t < 6; ++t) {
        const int G = wave + t * 8;
        const int d = G * 16 + l15;
        const float bias = b2[d];
        #pragma unroll
        for (int mh = 0; mh < 2; ++mh) {
            #pragma unroll
            for (int r = 0; r < 4; ++r) {
                int row = mh * 16 + lg * 4 + r;
                out[(rowBase + row) * DIM + d] = acc[t][mh][r] + bias;
            }
        }
    }
}

extern "C" void kernel_launch(void* const* d_in, const int* in_sizes, int n_in,
                              void* d_out, int out_size, void* d_ws, size_t ws_size,
                              hipStream_t stream) {
    const float* x = (const float*)d_in[0];
    const float* W1 = (const float*)d_in[1];
    const float* b1 = (const float*)d_in[2];
    const float* W2 = (const float*)d_in[3];
    const float* b2 = (const float*)d_in[4];
    const int* mask1 = (const int*)d_in[5];   // [384,96] int32 0/1
    const int* mask2 = (const int*)d_in[6];   // [96,384]
    float* out = (float*)d_out;

    // workspace layout (bf16/ushort region then int region), ~9.2 MB total
    unsigned short* W1c = (unsigned short*)d_ws;
    unsigned short* W2c = W1c + W1C_TOT;
    unsigned short* idx1 = W2c + W2C_TOT;
    unsigned short* idx2 = idx1 + IDX1_TOT;
    int* cnt1p = (int*)(idx2 + IDX2_TOT);
    int* off2 = cnt1p + NF16;

    bsffn_prep<<<NF16 + ND16, 256, 0, stream>>>(
        W1, W2, mask1, mask2,
        (__hip_bfloat16*)W1c, (__hip_bfloat16*)W2c, idx1, idx2, cnt1p, off2);

    const int rows = in_sizes[0] / DIM;        // 36928
    const int nblk = rows / MR;                // 1154 (exact)
    bsffn_main<<<nblk, 512, 0, stream>>>(
        x, b1, b2, W1c, W2c, idx1, idx2, cnt1p, off2, out);
}

// Round 6
// 433.998 us; speedup vs baseline: 45.9908x; 1.5026x over previous
//
#include <hip/hip_runtime.h>
#include <hip/hip_bf16.h>

// Block-sparse FFN via compacted-weight MFMA, v6 (latency-focused).
//   out = gelu(x @ (W1*M1)^T + b1) @ (W2*M2)^T + b2
// Prep: per 16-out-col group, union-compact nonzero 8-blocks, pad to x8 slots,
// gather masked weights as bf16 MFMA B-tiles (zero-filled pads) in d_ws.
// Main: 16 x-rows/block, 512 thr, 74.2KB LDS -> 2 blocks/CU (16 waves).
// Inner loop: 2 independent MFMA chains (8 slots/iter) + 1-ahead prefetch.
// fc2 idx lists stored chunk-local, pre-split & padded at the h-chunk boundary.

typedef __attribute__((ext_vector_type(8))) short short8;
typedef __attribute__((ext_vector_type(4))) float f32x4;
typedef unsigned long long u64;
typedef unsigned short ushort_t;

#define DIM 768
#define FF 3072
#define NF16 192            // FF/16  (fc1 groups)
#define ND16 48             // DIM/16 (fc2 groups)
#define NDB 96              // DIM/8
#define NFB 384             // FF/8
#define MR 16               // x rows per block
#define XP 776              // xs pitch (bf16): 768+8
#define HCH 1536            // h chunk width
#define HP 1544             // hs pitch (bf16): 1536+8
#define W1C_STRIDE 12288    // 96 slots * 128 elems
#define W2C_STRIDE 49152    // 384 slots * 128 elems
#define IDX2_STRIDE 384

#define W1C_TOT (NF16 * W1C_STRIDE)   // 2359296
#define W2C_TOT (ND16 * W2C_STRIDE)   // 2359296
#define IDX1_TOT (NF16 * 96)
#define IDX2_TOT (ND16 * IDX2_STRIDE)

__device__ __forceinline__ float gelu_fast(float v) {
    // x * sigmoid(1.5957691x + 0.07135548x^3)  (tanh-gelu identity), |err| <~ 5e-4
    float t = v * fmaf(v * v, 0.07135548f, 1.5957691f);
    return v / (1.0f + __expf(-t));
}
__device__ __forceinline__ ushort_t f2bs(float f) {
    union { __hip_bfloat16 h; ushort_t u; } cv;
    cv.h = __float2bfloat16(f);
    return cv.u;
}

// ---------------- preprocessing ----------------
__global__ __launch_bounds__(256)
void bsffn_prep(const float* __restrict__ W1, const float* __restrict__ W2,
                const int* __restrict__ mask1, const int* __restrict__ mask2,
                __hip_bfloat16* __restrict__ W1c, __hip_bfloat16* __restrict__ W2c,
                ushort_t* __restrict__ idx1, ushort_t* __restrict__ idx2,
                int* __restrict__ cnt1p, int* __restrict__ off2)
{
    __shared__ ushort_t sidx[400];
    __shared__ int sc[4];
    const int tid = threadIdx.x;
    const int l = tid & 63;
    const int g = blockIdx.x;

    if (g < NF16) {                       // ---- fc1 group F ----
        const int F = g;
        const int* r0 = mask1 + (2 * F) * NDB;
        const int* r1 = r0 + NDB;
        if (tid < 64) {
            bool ua = (r0[l] | r1[l]) != 0;
            u64 ba = __ballot(ua);
            bool ub = (l < 32) && ((r0[64 + l] | r1[64 + l]) != 0);
            u64 bb = __ballot(ub);
            int ca = __popcll(ba);
            if (ua) sidx[__popcll(ba & ((1ull << l) - 1ull))] = (ushort_t)l;
            if (ub) sidx[ca + __popcll(bb & ((1ull << l) - 1ull))] = (ushort_t)(64 + l);
            int cnt = ca + __popcll(bb);
            int cntp = (cnt + 7) & ~7;    // pad to x8 for dual-chain unroll
            if (l == 0) {
                for (int i = cnt; i < cntp; ++i) sidx[i] = 0;
                sc[0] = cnt; sc[1] = cntp;
                cnt1p[F] = cntp;
            }
        }
        __syncthreads();
        const int cnt = sc[0], cntp = sc[1];
        if (tid < cntp) idx1[F * 96 + tid] = sidx[tid];
        for (int e = tid; e < cntp * 128; e += 256) {
            int slot = e >> 7, r = (e >> 3) & 15, j = e & 7;
            int db = sidx[slot];
            float w = 0.f;
            if (slot < cnt && mask1[(2 * F + (r >> 3)) * NDB + db])
                w = W1[(long)(F * 16 + r) * DIM + db * 8 + j];
            W1c[(long)F * W1C_STRIDE + e] = __float2bfloat16(w);
        }
    } else {                              // ---- fc2 group G ----
        const int G = g - NF16;
        const int* r0 = mask2 + (2 * G) * NFB;
        const int* r1 = r0 + NFB;
        if (tid < 64) {
            u64 b[6]; int pc[6];
            #pragma unroll
            for (int p = 0; p < 6; ++p) {
                b[p] = __ballot((r0[p * 64 + l] | r1[p * 64 + l]) != 0);
                pc[p] = __popcll(b[p]);
            }
            int cnt0 = pc[0] + pc[1] + pc[2];
            int cnt1 = pc[3] + pc[4] + pc[5];
            int cnt0p = (cnt0 + 7) & ~7;
            int cnt1pp = (cnt1 + 7) & ~7;
            int base = 0;
            #pragma unroll
            for (int p = 0; p < 3; ++p) {          // chunk 0, local fb = global fb
                if ((b[p] >> l) & 1ull)
                    sidx[base + __popcll(b[p] & ((1ull << l) - 1ull))] = (ushort_t)(p * 64 + l);
                base += pc[p];
            }
            base = cnt0p;
            #pragma unroll
            for (int p = 3; p < 6; ++p) {          // chunk 1, local fb = global - 192
                if ((b[p] >> l) & 1ull)
                    sidx[base + __popcll(b[p] & ((1ull << l) - 1ull))] = (ushort_t)(p * 64 + l - 192);
                base += pc[p];
            }
            if (l == 0) {
                for (int i = cnt0; i < cnt0p; ++i) sidx[i] = 0;
                for (int i = cnt0p + cnt1; i < cnt0p + cnt1pp; ++i) sidx[i] = 0;
                sc[0] = cnt0; sc[1] = cnt0p; sc[2] = cnt1; sc[3] = cnt0p + cnt1pp;
                off2[G * 3 + 0] = 0;
                off2[G * 3 + 1] = cnt0p;
                off2[G * 3 + 2] = cnt0p + cnt1pp;
            }
        }
        __syncthreads();
        const int cnt0 = sc[0], cnt0p = sc[1], cnt1 = sc[2], total = sc[3];
        for (int t = tid; t < total; t += 256) idx2[G * IDX2_STRIDE + t] = sidx[t];
        for (int e = tid; e < total * 128; e += 256) {
            int slot = e >> 7, r = (e >> 3) & 15, j = e & 7;
            int lfb = sidx[slot];
            bool inC1 = slot >= cnt0p;
            bool real = inC1 ? (slot < cnt0p + cnt1) : (slot < cnt0);
            int fb = lfb + (inC1 ? 192 : 0);
            float w = 0.f;
            if (real && mask2[(2 * G + (r >> 3)) * NFB + fb])
                w = W2[(long)(G * 16 + r) * FF + fb * 8 + j];
            W2c[(long)G * W2C_STRIDE + e] = __float2bfloat16(w);
        }
    }
}

// ---------------- main fused kernel ----------------
__global__ __launch_bounds__(512, 4)
void bsffn_main(const float* __restrict__ x,
                const float* __restrict__ pb1, const float* __restrict__ pb2,
                const ushort_t* __restrict__ W1c, const ushort_t* __restrict__ W2c,
                const ushort_t* __restrict__ idx1, const ushort_t* __restrict__ idx2,
                const int* __restrict__ cnt1p, const int* __restrict__ off2,
                float* __restrict__ out)
{
    __shared__ __align__(16) ushort_t xs[MR * XP];   // 24,832 B
    __shared__ __align__(16) ushort_t hs[MR * HP];   // 49,408 B  (total 74,240 -> 2 blk/CU)

    const int tid = threadIdx.x;
    const int wave = tid >> 6;
    const int l = tid & 63;
    const int l15 = l & 15;
    const int lg = l >> 4;                 // k-slot subgroup 0..3
    const long rowBase = (long)blockIdx.x * MR;

    // ---- stage x tile -> bf16 LDS ----
    {
        const float* xr = x + rowBase * DIM;
        #pragma unroll
        for (int i = 0; i < 3; ++i) {
            int e = tid + i * 512;         // 0..1535 : 16 rows x 96 col-groups(8)
            int row = e / 96, c8 = e % 96;
            const float4 v0 = *(const float4*)(xr + row * DIM + c8 * 8);
            const float4 v1 = *(const float4*)(xr + row * DIM + c8 * 8 + 4);
            uint4 wv;
            wv.x = (unsigned)f2bs(v0.x) | ((unsigned)f2bs(v0.y) << 16);
            wv.y = (unsigned)f2bs(v0.z) | ((unsigned)f2bs(v0.w) << 16);
            wv.z = (unsigned)f2bs(v1.x) | ((unsigned)f2bs(v1.y) << 16);
            wv.w = (unsigned)f2bs(v1.z) | ((unsigned)f2bs(v1.w) << 16);
            *(uint4*)&xs[row * XP + c8 * 8] = wv;
        }
    }

    f32x4 acc[6];
    #pragma unroll
    for (int t = 0; t < 6; ++t) acc[t] = (f32x4){0.f, 0.f, 0.f, 0.f};

    __syncthreads();

    for (int chunk = 0; chunk < 2; ++chunk) {
        // ---- fc1: h[:, chunk*1536 .. +1536) = gelu(x W1^T + b1) ----
        int cnts[12];
        #pragma unroll
        for (int j = 0; j < 12; ++j) cnts[j] = cnt1p[chunk * 96 + wave * 12 + j];

        for (int j = 0; j < 12; ++j) {
            const int Fl = wave * 12 + j;          // within-chunk group 0..95
            const int F = chunk * 96 + Fl;
            const int cnt = cnts[j];               // multiple of 8
            const ushort_t* idxF = idx1 + F * 96;
            const ushort_t* wb = W1c + (long)F * W1C_STRIDE + lg * 128 + l15 * 8;
            f32x4 ca = {0.f, 0.f, 0.f, 0.f}, cb = {0.f, 0.f, 0.f, 0.f};
            if (cnt > 0) {
                int m0 = idxF[lg], m1 = idxF[4 + lg];
                short8 a0 = *(const short8*)&xs[l15 * XP + m0 * 8];
                short8 a1 = *(const short8*)&xs[l15 * XP + m1 * 8];
                short8 w0 = *(const short8*)(wb);
                short8 w1 = *(const short8*)(wb + 512);
                for (int s = 8; s < cnt; s += 8) {
                    int n0 = idxF[s + lg], n1 = idxF[s + 4 + lg];
                    short8 na0 = *(const short8*)&xs[l15 * XP + n0 * 8];
                    short8 na1 = *(const short8*)&xs[l15 * XP + n1 * 8];
                    short8 nw0 = *(const short8*)(wb + s * 128);
                    short8 nw1 = *(const short8*)(wb + s * 128 + 512);
                    ca = __builtin_amdgcn_mfma_f32_16x16x32_bf16(a0, w0, ca, 0, 0, 0);
                    cb = __builtin_amdgcn_mfma_f32_16x16x32_bf16(a1, w1, cb, 0, 0, 0);
                    a0 = na0; a1 = na1; w0 = nw0; w1 = nw1;
                }
                ca = __builtin_amdgcn_mfma_f32_16x16x32_bf16(a0, w0, ca, 0, 0, 0);
                cb = __builtin_amdgcn_mfma_f32_16x16x32_bf16(a1, w1, cb, 0, 0, 0);
            }
            const float bias = pb1[F * 16 + l15];
            #pragma unroll
            for (int r = 0; r < 4; ++r) {          // D: col=l15, row=lg*4+r
                float v = gelu_fast(ca[r] + cb[r] + bias);
                hs[(lg * 4 + r) * HP + Fl * 16 + l15] = f2bs(v);
            }
        }
        __syncthreads();

        // ---- fc2: accumulate out partials from this h chunk ----
        #pragma unroll
        for (int j = 0; j < 6; ++j) {
            const int G = wave * 6 + j;
            const int sbeg = off2[G * 3 + chunk];
            const int send = off2[G * 3 + chunk + 1];   // (send-sbeg) multiple of 8
            const ushort_t* idxG = idx2 + G * IDX2_STRIDE;
            const ushort_t* wb = W2c + (long)G * W2C_STRIDE + lg * 128 + l15 * 8;
            f32x4 ca = acc[j], cb = {0.f, 0.f, 0.f, 0.f};
            if (send > sbeg) {
                int m0 = idxG[sbeg + lg], m1 = idxG[sbeg + 4 + lg];   // chunk-local fb
                short8 a0 = *(const short8*)&hs[l15 * HP + m0 * 8];
                short8 a1 = *(const short8*)&hs[l15 * HP + m1 * 8];
                short8 w0 = *(const short8*)(wb + sbeg * 128);
                short8 w1 = *(const short8*)(wb + sbeg * 128 + 512);
                for (int s = sbeg + 8; s < send; s += 8) {
                    int n0 = idxG[s + lg], n1 = idxG[s + 4 + lg];
                    short8 na0 = *(const short8*)&hs[l15 * HP + n0 * 8];
                    short8 na1 = *(const short8*)&hs[l15 * HP + n1 * 8];
                    short8 nw0 = *(const short8*)(wb + s * 128);
                    short8 nw1 = *(const short8*)(wb + s * 128 + 512);
                    ca = __builtin_amdgcn_mfma_f32_16x16x32_bf16(a0, w0, ca, 0, 0, 0);
                    cb = __builtin_amdgcn_mfma_f32_16x16x32_bf16(a1, w1, cb, 0, 0, 0);
                    a0 = na0; a1 = na1; w0 = nw0; w1 = nw1;
                }
                ca = __builtin_amdgcn_mfma_f32_16x16x32_bf16(a0, w0, ca, 0, 0, 0);
                cb = __builtin_amdgcn_mfma_f32_16x16x32_bf16(a1, w1, cb, 0, 0, 0);
            }
            acc[j] = ca + cb;
        }
        __syncthreads();
    }

    // ---- epilogue: bias + store ----
    #pragma unroll
    for (int j = 0; j < 6; ++j) {
        const int G = wave * 6 + j;
        const int d = G * 16 + l15;
        const float bias = pb2[d];
        #pragma unroll
        for (int r = 0; r < 4; ++r) {
            int row = lg * 4 + r;
            out[(rowBase + row) * DIM + d] = acc[j][r] + bias;
        }
    }
}

extern "C" void kernel_launch(void* const* d_in, const int* in_sizes, int n_in,
                              void* d_out, int out_size, void* d_ws, size_t ws_size,
                              hipStream_t stream) {
    const float* x = (const float*)d_in[0];
    const float* W1 = (const float*)d_in[1];
    const float* b1 = (const float*)d_in[2];
    const float* W2 = (const float*)d_in[3];
    const float* b2 = (const float*)d_in[4];
    const int* mask1 = (const int*)d_in[5];   // [384,96] int32 0/1
    const int* mask2 = (const int*)d_in[6];   // [96,384]
    float* out = (float*)d_out;

    // workspace layout: ushort arrays then int arrays (~9.5 MB)
    ushort_t* W1c = (ushort_t*)d_ws;
    ushort_t* W2c = W1c + W1C_TOT;
    ushort_t* idx1 = W2c + W2C_TOT;
    ushort_t* idx2 = idx1 + IDX1_TOT;
    int* cnt1p = (int*)(idx2 + IDX2_TOT);
    int* off2 = cnt1p + NF16;

    bsffn_prep<<<NF16 + ND16, 256, 0, stream>>>(
        W1, W2, mask1, mask2,
        (__hip_bfloat16*)W1c, (__hip_bfloat16*)W2c, idx1, idx2, cnt1p, off2);

    const int rows = in_sizes[0] / DIM;        // 36928
    const int nblk = rows / MR;                // 2308 (exact)
    bsffn_main<<<nblk, 512, 0, stream>>>(
        x, b1, b2, W1c, W2c, idx1, idx2, cnt1p, off2, out);
}

// Round 7
// 340.660 us; speedup vs baseline: 58.5919x; 1.2740x over previous
//
#include <hip/hip_runtime.h>
#include <hip/hip_bf16.h>

// Block-sparse FFN via compacted-weight MFMA, v7 (flattened CSR streams).
//   out = gelu(x @ (W1*M1)^T + b1) @ (W2*M2)^T + b2
// Prep: count -> scan -> gather. Weights/indices stored as contiguous per-group
// streams (group order = wave order), slots padded to x8 (zero weight tiles).
// Main: 16 rows/block, 512 thr, 74.2 KB LDS (2 blk/CU). Per wave ONE linear
// slot stream per phase; persistent 1-ahead prefetch crosses group boundaries;
// idx via wave-uniform s_load; coalesced float4 epilogue through LDS.

typedef __attribute__((ext_vector_type(8))) short short8;
typedef __attribute__((ext_vector_type(4))) float f32x4;
typedef unsigned long long u64;
typedef unsigned short ushort_t;

#define DIM 768
#define FF 3072
#define NF16 192            // FF/16
#define ND16 48             // DIM/16
#define NDB 96              // DIM/8
#define NFB 384             // FF/8
#define MR 16               // x rows per block
#define XP 776              // xs pitch (bf16 elems)
#define HP 1544             // hs pitch (bf16 elems)

#define S1CAP (NF16 * 96)       // 18432 slots max
#define S2CAP (ND16 * 2 * 192)  // 18432 slots max
#define W1S_TOT (S1CAP * 128)
#define W2S_TOT (S2CAP * 128)

__device__ __forceinline__ float gelu_fast(float v) {
    // x * sigmoid(1.5957691x + 0.07135548x^3), |err| <~ 5e-4
    float t = v * fmaf(v * v, 0.07135548f, 1.5957691f);
    return v / (1.0f + __expf(-t));
}
__device__ __forceinline__ ushort_t f2bs(float f) {
    union { __hip_bfloat16 h; ushort_t u; } cv;
    cv.h = __float2bfloat16(f);
    return cv.u;
}

// ---------------- prep 1: per-group padded counts ----------------
__global__ __launch_bounds__(64)
void prep_count(const int* __restrict__ mask1, const int* __restrict__ mask2,
                int* __restrict__ off1, int* __restrict__ off2)
{
    const int l = threadIdx.x;
    const int g = blockIdx.x;
    if (g < NF16) {
        const int* r0 = mask1 + (2 * g) * NDB;
        const int* r1 = r0 + NDB;
        bool ua = (r0[l] | r1[l]) != 0;
        u64 ba = __ballot(ua);
        bool ub = (l < 32) && ((r0[64 + l] | r1[64 + l]) != 0);
        u64 bb = __ballot(ub);
        if (l == 0) {
            int cnt = __popcll(ba) + __popcll(bb);
            off1[g + 1] = (cnt + 7) & ~7;
        }
    } else {
        const int G = g - NF16;
        const int* r0 = mask2 + (2 * G) * NFB;
        const int* r1 = r0 + NFB;
        int c0 = 0, c1 = 0;
        #pragma unroll
        for (int p = 0; p < 6; ++p) {
            u64 b = __ballot((r0[p * 64 + l] | r1[p * 64 + l]) != 0);
            if (p < 3) c0 += __popcll(b); else c1 += __popcll(b);
        }
        if (l == 0) {
            off2[0 * ND16 + G + 1] = (c0 + 7) & ~7;   // chunk-major position G
            off2[1 * ND16 + G + 1] = (c1 + 7) & ~7;   // position 48+G
        }
    }
}

// ---------------- prep 2: serial prefix scan (tiny) ----------------
__global__ __launch_bounds__(64)
void prep_scan(int* __restrict__ off1, int* __restrict__ off2)
{
    if (threadIdx.x == 0) {
        off1[0] = 0;
        for (int i = 0; i < NF16; ++i) off1[i + 1] += off1[i];
    } else if (threadIdx.x == 1) {
        off2[0] = 0;
        for (int i = 0; i < 2 * ND16; ++i) off2[i + 1] += off2[i];
    }
}

// ---------------- prep 3: gather compacted weights + indices ----------------
__global__ __launch_bounds__(256)
void prep_gather(const float* __restrict__ W1, const float* __restrict__ W2,
                 const int* __restrict__ mask1, const int* __restrict__ mask2,
                 const int* __restrict__ off1, const int* __restrict__ off2,
                 __hip_bfloat16* __restrict__ w1s, __hip_bfloat16* __restrict__ w2s,
                 ushort_t* __restrict__ idx1s, ushort_t* __restrict__ idx2s)
{
    __shared__ ushort_t sidx[192];
    __shared__ int sc[1];
    const int tid = threadIdx.x;
    const int l = tid & 63;
    const int g = blockIdx.x;

    if (g < NF16) {                       // ---- fc1 group F ----
        const int F = g;
        const int* r0 = mask1 + (2 * F) * NDB;
        const int* r1 = r0 + NDB;
        if (tid < 64) {
            bool ua = (r0[l] | r1[l]) != 0;
            u64 ba = __ballot(ua);
            bool ub = (l < 32) && ((r0[64 + l] | r1[64 + l]) != 0);
            u64 bb = __ballot(ub);
            int ca = __popcll(ba);
            if (ua) sidx[__popcll(ba & ((1ull << l) - 1ull))] = (ushort_t)l;
            if (ub) sidx[ca + __popcll(bb & ((1ull << l) - 1ull))] = (ushort_t)(64 + l);
            int cnt = ca + __popcll(bb);
            if (l == 0) {
                sc[0] = cnt;
                int cntp = (cnt + 7) & ~7;
                for (int i = cnt; i < cntp; ++i) sidx[i] = 0;
            }
        }
        __syncthreads();
        const int cnt = sc[0];
        const int base = off1[F];
        const int cntp = off1[F + 1] - base;
        if (tid < cntp) idx1s[base + tid] = sidx[tid];
        for (int e = tid; e < cntp * 128; e += 256) {
            int slot = e >> 7, r = (e >> 3) & 15, j = e & 7;
            int db = sidx[slot];
            float w = 0.f;
            if (slot < cnt && mask1[(2 * F + (r >> 3)) * NDB + db])
                w = W1[(long)(F * 16 + r) * DIM + db * 8 + j];
            w1s[(long)base * 128 + e] = __float2bfloat16(w);
        }
    } else {                              // ---- fc2 (chunk, G) ----
        const int gi = g - NF16;
        const int c = gi / ND16;
        const int G = gi % ND16;
        const int* r0 = mask2 + (2 * G) * NFB;
        const int* r1 = r0 + NFB;
        if (tid < 64) {
            u64 b[3]; int pc[3];
            #pragma unroll
            for (int p = 0; p < 3; ++p) {
                int fb = c * 192 + p * 64 + l;
                b[p] = __ballot((r0[fb] | r1[fb]) != 0);
                pc[p] = __popcll(b[p]);
            }
            int basea = 0;
            #pragma unroll
            for (int p = 0; p < 3; ++p) {
                if ((b[p] >> l) & 1ull)
                    sidx[basea + __popcll(b[p] & ((1ull << l) - 1ull))] = (ushort_t)(p * 64 + l);
                basea += pc[p];
            }
            if (l == 0) {
                int cnt = basea;
                sc[0] = cnt;
                int cntp = (cnt + 7) & ~7;
                for (int i = cnt; i < cntp; ++i) sidx[i] = 0;
            }
        }
        __syncthreads();
        const int cnt = sc[0];
        const int base = off2[c * ND16 + G];
        const int cntp = off2[c * ND16 + G + 1] - base;
        if (tid < cntp) idx2s[base + tid] = sidx[tid];
        for (int e = tid; e < cntp * 128; e += 256) {
            int slot = e >> 7, r = (e >> 3) & 15, j = e & 7;
            int lfb = sidx[slot];                 // chunk-local fb (0..191)
            int fb = c * 192 + lfb;
            float w = 0.f;
            if (slot < cnt && mask2[(2 * G + (r >> 3)) * NFB + fb])
                w = W2[(long)(G * 16 + r) * FF + fb * 8 + j];
            w2s[(long)base * 128 + e] = __float2bfloat16(w);
        }
    }
}

// ---------------- main fused kernel ----------------
// prefetch one 8-slot window (2 MFMAs) ahead; works across group boundaries.
#define PREF(IDXS, WS, ARR, ROWOFF)                                          \
    {                                                                        \
        int sp = (s < sEnd) ? s : sEnd - 8;                                  \
        uint4 q = *(const uint4*)(IDXS + sp);                                \
        unsigned dd0 = (lg & 2) ? q.y : q.x;                                 \
        unsigned dd1 = (lg & 2) ? q.w : q.z;                                 \
        int m0 = (int)((dd0 >> shsel) & 0xffffu);                            \
        int m1 = (int)((dd1 >> shsel) & 0xffffu);                            \
        pa0 = *(const short8*)&ARR[ROWOFF + m0 * 8];                         \
        pa1 = *(const short8*)&ARR[ROWOFF + m1 * 8];                         \
        const ushort_t* wp = WS + (long)sp * 128 + lofs;                     \
        pw0 = *(const short8*)(wp);                                          \
        pw1 = *(const short8*)(wp + 512);                                    \
    }

#define STEP(IDXS, WS, ARR, ROWOFF)                                          \
    {                                                                        \
        short8 a0 = pa0, a1 = pa1, w0 = pw0, w1 = pw1;                       \
        s += 8;                                                              \
        PREF(IDXS, WS, ARR, ROWOFF)                                          \
        ca = __builtin_amdgcn_mfma_f32_16x16x32_bf16(a0, w0, ca, 0, 0, 0);   \
        cb = __builtin_amdgcn_mfma_f32_16x16x32_bf16(a1, w1, cb, 0, 0, 0);   \
    }

__global__ __launch_bounds__(512, 4)
void bsffn_main(const float* __restrict__ x,
                const float* __restrict__ pb1, const float* __restrict__ pb2,
                const ushort_t* __restrict__ w1s, const ushort_t* __restrict__ w2s,
                const ushort_t* __restrict__ idx1s, const ushort_t* __restrict__ idx2s,
                const int* __restrict__ off1, const int* __restrict__ off2,
                float* __restrict__ out)
{
    __shared__ __align__(16) ushort_t xs[MR * XP];   // 24,832 B
    __shared__ __align__(16) ushort_t hs[MR * HP];   // 49,408 B (reused as f32 sacc)

    const int tid = threadIdx.x;
    const int wave = tid >> 6;
    const int l = tid & 63;
    const int l15 = l & 15;
    const int lg = l >> 4;
    const int xrow = l15 * XP;
    const int hrow = l15 * HP;
    const int lofs = lg * 128 + l15 * 8;
    const unsigned shsel = (unsigned)((lg & 1) << 4);
    const long rowBase = (long)blockIdx.x * MR;

    // ---- stage x tile -> bf16 LDS ----
    {
        const float* xr = x + rowBase * DIM;
        #pragma unroll
        for (int i = 0; i < 3; ++i) {
            int e = tid + i * 512;         // 16 rows x 96 col-groups(8)
            int row = e / 96, c8 = e % 96;
            const float4 v0 = *(const float4*)(xr + row * DIM + c8 * 8);
            const float4 v1 = *(const float4*)(xr + row * DIM + c8 * 8 + 4);
            uint4 wv;
            wv.x = (unsigned)f2bs(v0.x) | ((unsigned)f2bs(v0.y) << 16);
            wv.y = (unsigned)f2bs(v0.z) | ((unsigned)f2bs(v0.w) << 16);
            wv.z = (unsigned)f2bs(v1.x) | ((unsigned)f2bs(v1.y) << 16);
            wv.w = (unsigned)f2bs(v1.z) | ((unsigned)f2bs(v1.w) << 16);
            *(uint4*)&xs[row * XP + c8 * 8] = wv;
        }
    }

    f32x4 acc[6];
    #pragma unroll
    for (int t = 0; t < 6; ++t) acc[t] = (f32x4){0.f, 0.f, 0.f, 0.f};

    __syncthreads();

    for (int chunk = 0; chunk < 2; ++chunk) {
        // ---------- fc1: one linear stream over the wave's 12 groups ----------
        {
            const int Fbeg = chunk * 96 + wave * 12;
            int s = off1[Fbeg];
            const int sEnd = off1[Fbeg + 12];
            short8 pa0 = {0,0,0,0,0,0,0,0}, pa1 = pa0, pw0 = pa0, pw1 = pa0;
            if (s < sEnd) PREF(idx1s, w1s, xs, xrow)
            #pragma unroll 1
            for (int j = 0; j < 12; ++j) {
                const int F = Fbeg + j;
                const int gend = off1[F + 1];
                const float bias = pb1[F * 16 + l15];
                f32x4 ca = {0.f,0.f,0.f,0.f}, cb = {0.f,0.f,0.f,0.f};
                while (s < gend) STEP(idx1s, w1s, xs, xrow)
                const int Fl = F - chunk * 96;
                #pragma unroll
                for (int r = 0; r < 4; ++r) {      // D: col=l15, row=lg*4+r
                    float v = gelu_fast(ca[r] + cb[r] + bias);
                    hs[(lg * 4 + r) * HP + Fl * 16 + l15] = f2bs(v);
                }
            }
        }
        __syncthreads();

        // ---------- fc2: one linear stream over the wave's 6 groups ----------
        {
            const int Pbeg = chunk * ND16 + wave * 6;
            int s = off2[Pbeg];
            const int sEnd = off2[Pbeg + 6];
            short8 pa0 = {0,0,0,0,0,0,0,0}, pa1 = pa0, pw0 = pa0, pw1 = pa0;
            if (s < sEnd) PREF(idx2s, w2s, hs, hrow)
#define FC2G(J)                                                              \
            {                                                                \
                const int gend = off2[Pbeg + (J) + 1];                       \
                f32x4 ca = acc[J], cb = {0.f,0.f,0.f,0.f};                   \
                while (s < gend) STEP(idx2s, w2s, hs, hrow)                  \
                acc[J] = ca + cb;                                            \
            }
            FC2G(0) FC2G(1) FC2G(2) FC2G(3) FC2G(4) FC2G(5)
#undef FC2G
        }
        __syncthreads();
    }

    // ---- epilogue: acc -> LDS (f32) -> coalesced float4 stores ----
    float* sacc = (float*)hs;                       // [16][772]
    #pragma unroll
    for (int j = 0; j < 6; ++j) {
        const int d = (wave * 6 + j) * 16 + l15;
        #pragma unroll
        for (int r = 0; r < 4; ++r)
            sacc[(lg * 4 + r) * 772 + d] = acc[j][r];
    }
    __syncthreads();
    {
        const float4* pb24 = (const float4*)pb2;
        #pragma unroll
        for (int i = 0; i < 6; ++i) {
            int e = tid + i * 512;                  // 16 rows x 192 float4
            int row = e / 192, c4 = e % 192;
            float4 v = *(const float4*)&sacc[row * 772 + c4 * 4];
            float4 b = pb24[c4];
            v.x += b.x; v.y += b.y; v.z += b.z; v.w += b.w;
            *(float4*)&out[(rowBase + row) * DIM + c4 * 4] = v;
        }
    }
}

extern "C" void kernel_launch(void* const* d_in, const int* in_sizes, int n_in,
                              void* d_out, int out_size, void* d_ws, size_t ws_size,
                              hipStream_t stream) {
    const float* x = (const float*)d_in[0];
    const float* W1 = (const float*)d_in[1];
    const float* b1 = (const float*)d_in[2];
    const float* W2 = (const float*)d_in[3];
    const float* b2 = (const float*)d_in[4];
    const int* mask1 = (const int*)d_in[5];   // [384,96] int32 0/1
    const int* mask2 = (const int*)d_in[6];   // [96,384]
    float* out = (float*)d_out;

    // ws layout: w1s | w2s | idx1s | idx2s | off1[193] | off2[97]  (~9.1 MiB)
    ushort_t* w1s = (ushort_t*)d_ws;
    ushort_t* w2s = w1s + W1S_TOT;
    ushort_t* idx1s = w2s + W2S_TOT;
    ushort_t* idx2s = idx1s + S1CAP;
    int* off1 = (int*)(idx2s + S2CAP);
    int* off2 = off1 + (NF16 + 1);

    prep_count<<<NF16 + ND16, 64, 0, stream>>>(mask1, mask2, off1, off2);
    prep_scan<<<1, 64, 0, stream>>>(off1, off2);
    prep_gather<<<NF16 + 2 * ND16, 256, 0, stream>>>(
        W1, W2, mask1, mask2, off1, off2,
        (__hip_bfloat16*)w1s, (__hip_bfloat16*)w2s, idx1s, idx2s);

    const int rows = in_sizes[0] / DIM;        // 36928
    const int nblk = rows / MR;                // 2308
    bsffn_main<<<nblk, 512, 0, stream>>>(
        x, b1, b2, w1s, w2s, idx1s, idx2s, off1, off2, out);
}

// Round 8
// 335.846 us; speedup vs baseline: 59.4318x; 1.0143x over previous
//
#include <hip/hip_runtime.h>
#include <hip/hip_bf16.h>

// Block-sparse FFN via compacted-weight MFMA, v8 (MR=32, 2-deep prefetch).
//   out = gelu(x @ (W1*M1)^T + b1) @ (W2*M2)^T + b2
// Prep: count -> scan -> gather. Contiguous per-group weight/idx streams in wave
// order, slots padded to x16 (zero weight tiles), stream tail over-allocated so
// prefetch may read past the end harmlessly.
// Main: 32 x-rows/block, 512 thr, 148.5 KB LDS (1 blk/CU, 8 waves). Each 8-slot
// window: 2 B-tiles x 2 row-halves = 4 MFMAs. Pair-window loop = 2-deep prefetch
// with running pointers. Coalesced float4 epilogue through LDS.

typedef __attribute__((ext_vector_type(8))) short short8;
typedef __attribute__((ext_vector_type(4))) float f32x4;
typedef unsigned long long u64;
typedef unsigned short ushort_t;

#define DIM 768
#define FF 3072
#define NF16 192            // FF/16
#define ND16 48             // DIM/16
#define NDB 96              // DIM/8
#define NFB 384             // FF/8
#define MR 32               // x rows per block
#define XP 776              // xs pitch (bf16 elems), row stride 1552 B
#define HP 1544             // hs pitch (bf16 elems), row stride 3088 B
#define XSEC (16 * XP)      // elem offset of x rows 16..31  (24,832 B imm)
#define HSEC (16 * HP)      // elem offset of h rows 16..31  (49,408 B imm)

#define S1CAP (NF16 * 96 + 32)       // + tail margin for prefetch overrun
#define S2CAP (ND16 * 2 * 192 + 32)
#define W1S_TOT (S1CAP * 128)
#define W2S_TOT (S2CAP * 128)

#define MFMA __builtin_amdgcn_mfma_f32_16x16x32_bf16

__device__ __forceinline__ float gelu_fast(float v) {
    // x * sigmoid(1.5957691x + 0.07135548x^3), |err| <~ 5e-4
    float t2 = v * fmaf(v * v, -0.10295667f, -2.30235629f); // pre-scaled by ln2^-1 * -1? no: -1.4427 fold
    // t2 = -1.442695 * (1.5957691 v + 0.07135548 v^3): use exp2 directly
    return v / (1.0f + exp2f(t2));
}
__device__ __forceinline__ ushort_t f2bs(float f) {
    union { __hip_bfloat16 h; ushort_t u; } cv;
    cv.h = __float2bfloat16(f);
    return cv.u;
}

// ---------------- prep 1: per-group padded counts ----------------
__global__ __launch_bounds__(64)
void prep_count(const int* __restrict__ mask1, const int* __restrict__ mask2,
                int* __restrict__ off1, int* __restrict__ off2)
{
    const int l = threadIdx.x;
    const int g = blockIdx.x;
    if (g < NF16) {
        const int* r0 = mask1 + (2 * g) * NDB;
        const int* r1 = r0 + NDB;
        bool ua = (r0[l] | r1[l]) != 0;
        u64 ba = __ballot(ua);
        bool ub = (l < 32) && ((r0[64 + l] | r1[64 + l]) != 0);
        u64 bb = __ballot(ub);
        if (l == 0) {
            int cnt = __popcll(ba) + __popcll(bb);
            off1[g + 1] = (cnt + 15) & ~15;
        }
    } else {
        const int G = g - NF16;
        const int* r0 = mask2 + (2 * G) * NFB;
        const int* r1 = r0 + NFB;
        int c0 = 0, c1 = 0;
        #pragma unroll
        for (int p = 0; p < 6; ++p) {
            u64 b = __ballot((r0[p * 64 + l] | r1[p * 64 + l]) != 0);
            if (p < 3) c0 += __popcll(b); else c1 += __popcll(b);
        }
        if (l == 0) {
            off2[0 * ND16 + G + 1] = (c0 + 15) & ~15;
            off2[1 * ND16 + G + 1] = (c1 + 15) & ~15;
        }
    }
}

// ---------------- prep 2: serial prefix scan (tiny) ----------------
__global__ __launch_bounds__(64)
void prep_scan(int* __restrict__ off1, int* __restrict__ off2)
{
    if (threadIdx.x == 0) {
        off1[0] = 0;
        for (int i = 0; i < NF16; ++i) off1[i + 1] += off1[i];
    } else if (threadIdx.x == 1) {
        off2[0] = 0;
        for (int i = 0; i < 2 * ND16; ++i) off2[i + 1] += off2[i];
    }
}

// ---------------- prep 3: gather compacted weights + indices ----------------
__global__ __launch_bounds__(256)
void prep_gather(const float* __restrict__ W1, const float* __restrict__ W2,
                 const int* __restrict__ mask1, const int* __restrict__ mask2,
                 const int* __restrict__ off1, const int* __restrict__ off2,
                 __hip_bfloat16* __restrict__ w1s, __hip_bfloat16* __restrict__ w2s,
                 ushort_t* __restrict__ idx1s, ushort_t* __restrict__ idx2s)
{
    __shared__ ushort_t sidx[192];
    __shared__ int sc[1];
    const int tid = threadIdx.x;
    const int l = tid & 63;
    const int g = blockIdx.x;

    if (g < NF16) {                       // ---- fc1 group F ----
        const int F = g;
        const int* r0 = mask1 + (2 * F) * NDB;
        const int* r1 = r0 + NDB;
        if (tid < 64) {
            bool ua = (r0[l] | r1[l]) != 0;
            u64 ba = __ballot(ua);
            bool ub = (l < 32) && ((r0[64 + l] | r1[64 + l]) != 0);
            u64 bb = __ballot(ub);
            int ca = __popcll(ba);
            if (ua) sidx[__popcll(ba & ((1ull << l) - 1ull))] = (ushort_t)l;
            if (ub) sidx[ca + __popcll(bb & ((1ull << l) - 1ull))] = (ushort_t)(64 + l);
            int cnt = ca + __popcll(bb);
            if (l == 0) {
                sc[0] = cnt;
                int cntp = (cnt + 15) & ~15;
                for (int i = cnt; i < cntp && i < 192; ++i) sidx[i] = 0;
            }
        }
        __syncthreads();
        const int cnt = sc[0];
        const int base = off1[F];
        const int cntp = off1[F + 1] - base;
        if (tid < cntp) idx1s[base + tid] = sidx[tid];
        for (int e = tid; e < cntp * 128; e += 256) {
            int slot = e >> 7, r = (e >> 3) & 15, j = e & 7;
            int db = sidx[slot];
            float w = 0.f;
            if (slot < cnt && mask1[(2 * F + (r >> 3)) * NDB + db])
                w = W1[(long)(F * 16 + r) * DIM + db * 8 + j];
            w1s[(long)base * 128 + e] = __float2bfloat16(w);
        }
    } else {                              // ---- fc2 (chunk, G) ----
        const int gi = g - NF16;
        const int c = gi / ND16;
        const int G = gi % ND16;
        const int* r0 = mask2 + (2 * G) * NFB;
        const int* r1 = r0 + NFB;
        if (tid < 64) {
            u64 b[3]; int pc[3];
            #pragma unroll
            for (int p = 0; p < 3; ++p) {
                int fb = c * 192 + p * 64 + l;
                b[p] = __ballot((r0[fb] | r1[fb]) != 0);
                pc[p] = __popcll(b[p]);
            }
            int basea = 0;
            #pragma unroll
            for (int p = 0; p < 3; ++p) {
                if ((b[p] >> l) & 1ull)
                    sidx[basea + __popcll(b[p] & ((1ull << l) - 1ull))] = (ushort_t)(p * 64 + l);
                basea += pc[p];
            }
            if (l == 0) {
                int cnt = basea;
                sc[0] = cnt;
                int cntp = (cnt + 15) & ~15;
                for (int i = cnt; i < cntp && i < 192; ++i) sidx[i] = 0;
            }
        }
        __syncthreads();
        const int cnt = sc[0];
        const int base = off2[c * ND16 + G];
        const int cntp = off2[c * ND16 + G + 1] - base;
        if (tid < cntp) idx2s[base + tid] = sidx[tid];
        for (int e = tid; e < cntp * 128; e += 256) {
            int slot = e >> 7, r = (e >> 3) & 15, j = e & 7;
            int lfb = sidx[slot];                 // chunk-local fb (0..191)
            int fb = c * 192 + lfb;
            float w = 0.f;
            if (slot < cnt && mask2[(2 * G + (r >> 3)) * NFB + fb])
                w = W2[(long)(G * 16 + r) * FF + fb * 8 + j];
            w2s[(long)base * 128 + e] = __float2bfloat16(w);
        }
    }
}

// ---------------- main fused kernel ----------------
// Load one 8-slot window into register buffer BUF from idx ptr IP / weight ptr WP.
// A-fragments: rows 0-15 and 16-31 (same addr + imm offset SECOFF).
#define PREF(BUF, IP, WP, ARR, ROWOFF, SECOFF)                          \
    {                                                                   \
        uint4 q = *(const uint4*)(IP);                                  \
        unsigned dd0 = (lg & 2) ? q.y : q.x;                            \
        unsigned dd1 = (lg & 2) ? q.w : q.z;                            \
        int mo0 = (int)((dd0 >> shsel) & 0xffffu) * 8;                  \
        int mo1 = (int)((dd1 >> shsel) & 0xffffu) * 8;                  \
        BUF##a0 = *(const short8*)&ARR[ROWOFF + mo0];                   \
        BUF##a1 = *(const short8*)&ARR[ROWOFF + SECOFF + mo0];          \
        BUF##a2 = *(const short8*)&ARR[ROWOFF + mo1];                   \
        BUF##a3 = *(const short8*)&ARR[ROWOFF + SECOFF + mo1];          \
        BUF##w0 = *(const short8*)(WP);                                 \
        BUF##w1 = *(const short8*)(WP + 512);                           \
    }

// One pair of windows (16 slots): consume A (slots s), reload A <- s+16;
// consume B (slots s+8), reload B <- s+24. 8 MFMAs per iteration.
#define PAIRSTEP(IP, WP, ARR, ROWOFF, SECOFF)                           \
    {                                                                   \
        short8 t0 = Aa0, t1 = Aa1, t2 = Aa2, t3 = Aa3, u0 = Aw0, u1 = Aw1; \
        PREF(A, IP, WP, ARR, ROWOFF, SECOFF)                            \
        ca = MFMA(t0, u0, ca, 0, 0, 0); cc = MFMA(t1, u0, cc, 0, 0, 0); \
        cb = MFMA(t2, u1, cb, 0, 0, 0); cd = MFMA(t3, u1, cd, 0, 0, 0); \
    }                                                                   \
    {                                                                   \
        short8 t0 = Ba0, t1 = Ba1, t2 = Ba2, t3 = Ba3, u0 = Bw0, u1 = Bw1; \
        PREF(B, (IP + 8), (WP + 1024), ARR, ROWOFF, SECOFF)             \
        ca = MFMA(t0, u0, ca, 0, 0, 0); cc = MFMA(t1, u0, cc, 0, 0, 0); \
        cb = MFMA(t2, u1, cb, 0, 0, 0); cd = MFMA(t3, u1, cd, 0, 0, 0); \
    }                                                                   \
    IP += 16; WP += 2048; s += 16;

__global__ __launch_bounds__(512, 2)
void bsffn_main(const float* __restrict__ x,
                const float* __restrict__ pb1, const float* __restrict__ pb2,
                const ushort_t* __restrict__ w1s, const ushort_t* __restrict__ w2s,
                const ushort_t* __restrict__ idx1s, const ushort_t* __restrict__ idx2s,
                const int* __restrict__ off1, const int* __restrict__ off2,
                float* __restrict__ out)
{
    __shared__ __align__(16) ushort_t xs[MR * XP];   // 49,664 B
    __shared__ __align__(16) ushort_t hs[MR * HP];   // 98,816 B (reused as f32 sacc)

    const int tid = threadIdx.x;
    const int wave = tid >> 6;
    const int l = tid & 63;
    const int l15 = l & 15;
    const int lg = l >> 4;
    const int xrow = l15 * XP;
    const int hrow = l15 * HP;
    const int lofs = lg * 128 + l15 * 8;
    const unsigned shsel = (unsigned)((lg & 1) << 4);
    const long rowBase = (long)blockIdx.x * MR;

    // ---- stage x tile -> bf16 LDS ----
    {
        const float* xr = x + rowBase * DIM;
        #pragma unroll
        for (int i = 0; i < 6; ++i) {
            int e = tid + i * 512;         // 32 rows x 96 col-groups(8)
            int row = e / 96, c8 = e % 96;
            const float4 v0 = *(const float4*)(xr + row * DIM + c8 * 8);
            const float4 v1 = *(const float4*)(xr + row * DIM + c8 * 8 + 4);
            uint4 wv;
            wv.x = (unsigned)f2bs(v0.x) | ((unsigned)f2bs(v0.y) << 16);
            wv.y = (unsigned)f2bs(v0.z) | ((unsigned)f2bs(v0.w) << 16);
            wv.z = (unsigned)f2bs(v1.x) | ((unsigned)f2bs(v1.y) << 16);
            wv.w = (unsigned)f2bs(v1.z) | ((unsigned)f2bs(v1.w) << 16);
            *(uint4*)&xs[row * XP + c8 * 8] = wv;
        }
    }

    f32x4 acc0[6], acc1[6];
    #pragma unroll
    for (int t = 0; t < 6; ++t) {
        acc0[t] = (f32x4){0.f, 0.f, 0.f, 0.f};
        acc1[t] = (f32x4){0.f, 0.f, 0.f, 0.f};
    }

    __syncthreads();

    for (int chunk = 0; chunk < 2; ++chunk) {
        // ---------- fc1: linear stream over the wave's 12 groups ----------
        {
            const int Fbeg = chunk * 96 + wave * 12;
            int s = off1[Fbeg];
            const ushort_t* ip = idx1s + s;
            const ushort_t* wp = w1s + (long)s * 128 + lofs;
            short8 Aa0, Aa1, Aa2, Aa3, Aw0, Aw1, Ba0, Ba1, Ba2, Ba3, Bw0, Bw1;
            PREF(A, ip, wp, xs, xrow, XSEC)
            PREF(B, (ip + 8), (wp + 1024), xs, xrow, XSEC)
            ip += 16; wp += 2048;
            #pragma unroll 1
            for (int j = 0; j < 12; ++j) {
                const int F = Fbeg + j;
                const int gend = off1[F + 1];
                f32x4 ca = {0.f,0.f,0.f,0.f}, cb = ca, cc = ca, cd = ca;
                while (s < gend) { PAIRSTEP(ip, wp, xs, xrow, XSEC) }
                const float bias = pb1[F * 16 + l15];
                const int hcol = (F - chunk * 96) * 16 + l15;
                #pragma unroll
                for (int r = 0; r < 4; ++r) {      // D: col=l15, row=lg*4+r
                    hs[(lg * 4 + r) * HP + hcol] = f2bs(gelu_fast(ca[r] + cb[r] + bias));
                    hs[HSEC + (lg * 4 + r) * HP + hcol] = f2bs(gelu_fast(cc[r] + cd[r] + bias));
                }
            }
        }
        __syncthreads();

        // ---------- fc2: linear stream over the wave's 6 groups ----------
        {
            const int Pbeg = chunk * ND16 + wave * 6;
            int s = off2[Pbeg];
            const ushort_t* ip = idx2s + s;
            const ushort_t* wp = w2s + (long)s * 128 + lofs;
            short8 Aa0, Aa1, Aa2, Aa3, Aw0, Aw1, Ba0, Ba1, Ba2, Ba3, Bw0, Bw1;
            PREF(A, ip, wp, hs, hrow, HSEC)
            PREF(B, (ip + 8), (wp + 1024), hs, hrow, HSEC)
            ip += 16; wp += 2048;
#define FC2G(J)                                                          \
            {                                                            \
                const int gend = off2[Pbeg + (J) + 1];                   \
                f32x4 ca = acc0[J], cc = acc1[J];                        \
                f32x4 cb = {0.f,0.f,0.f,0.f}, cd = cb;                   \
                while (s < gend) { PAIRSTEP(ip, wp, hs, hrow, HSEC) }    \
                acc0[J] = ca + cb; acc1[J] = cc + cd;                    \
            }
            FC2G(0) FC2G(1) FC2G(2) FC2G(3) FC2G(4) FC2G(5)
#undef FC2G
        }
        __syncthreads();
    }

    // ---- epilogue: acc -> LDS (f32) -> coalesced float4 stores ----
    float* sacc = (float*)hs;                       // [32][772]
    #pragma unroll
    for (int j = 0; j < 6; ++j) {
        const int d = (wave * 6 + j) * 16 + l15;
        #pragma unroll
        for (int r = 0; r < 4; ++r) {
            sacc[(lg * 4 + r) * 772 + d] = acc0[j][r];
            sacc[(16 + lg * 4 + r) * 772 + d] = acc1[j][r];
        }
    }
    __syncthreads();
    {
        const float4* pb24 = (const float4*)pb2;
        #pragma unroll
        for (int i = 0; i < 12; ++i) {
            int e = tid + i * 512;                  // 32 rows x 192 float4
            int row = e / 192, c4 = e % 192;
            float4 v = *(const float4*)&sacc[row * 772 + c4 * 4];
            float4 b = pb24[c4];
            v.x += b.x; v.y += b.y; v.z += b.z; v.w += b.w;
            *(float4*)&out[(rowBase + row) * DIM + c4 * 4] = v;
        }
    }
}

extern "C" void kernel_launch(void* const* d_in, const int* in_sizes, int n_in,
                              void* d_out, int out_size, void* d_ws, size_t ws_size,
                              hipStream_t stream) {
    const float* x = (const float*)d_in[0];
    const float* W1 = (const float*)d_in[1];
    const float* b1 = (const float*)d_in[2];
    const float* W2 = (const float*)d_in[3];
    const float* b2 = (const float*)d_in[4];
    const int* mask1 = (const int*)d_in[5];   // [384,96] int32 0/1
    const int* mask2 = (const int*)d_in[6];   // [96,384]
    float* out = (float*)d_out;

    // ws layout: w1s | w2s | idx1s | idx2s | off1[193] | off2[97]  (~9.5 MiB)
    ushort_t* w1s = (ushort_t*)d_ws;
    ushort_t* w2s = w1s + W1S_TOT;
    ushort_t* idx1s = w2s + W2S_TOT;
    ushort_t* idx2s = idx1s + S1CAP;
    int* off1 = (int*)(idx2s + S2CAP);
    int* off2 = off1 + (NF16 + 1);

    prep_count<<<NF16 + ND16, 64, 0, stream>>>(mask1, mask2, off1, off2);
    prep_scan<<<1, 64, 0, stream>>>(off1, off2);
    prep_gather<<<NF16 + 2 * ND16, 256, 0, stream>>>(
        W1, W2, mask1, mask2, off1, off2,
        (__hip_bfloat16*)w1s, (__hip_bfloat16*)w2s, idx1s, idx2s);

    const int rows = in_sizes[0] / DIM;        // 36928
    const int nblk = rows / MR;                // 1154
    bsffn_main<<<nblk, 512, 0, stream>>>(
        x, b1, b2, w1s, w2s, idx1s, idx2s, off1, off2, out);
}